// Round 12
// baseline (348.560 us; speedup 1.0000x reference)
//
#include <hip/hip_runtime.h>
#include <math.h>

// Problem constants (match reference)
constexpr int B = 256;
constexpr int T = 16384;
constexpr int K = 3;

// R18: single-launch fusion WITHOUT cooperative API. R11's coop launch
// no-oped (absmax 2.28 == max|u_ref| => outputs were zeros; error return
// unchecked). Replacement: 1024 blocks in ONE standard launch; blocks
// 0..511 = R10 conv tiles (bit-identical), 512..1023 = R10 scan tasks
// (bit-identical). Ordering via one-directional producer->consumer flags:
// conv publishes flags[blk] (threadfence + agent-scope release store);
// scan acquire-spins on the <=5 tiles it needs (acquire also invalidates
// stale L2 lines across XCDs/graph replays). Conv never waits -> no
// deadlock under ANY dispatch order; ascending order gives conv-first
// fill + scan streaming in as conv retires (panel L2 writeback overlaps
// instead of serializing at a kernel boundary, which cost ~60us:
// conv<=73 + scan=73 vs total=208 at R10).
constexpr int CHUNK = 128;
constexpr int WARM  = 512;

// Conv tiling: 64 chains x 128 timesteps per block, 4 waves x 32 t each.
constexpr int CBT = 128;
constexpr int CWT = 32;

// w32 panel layout [T/16][4 bg][12 q][64 lane] x 16B (float4):
// float4 q of lane i = stream floats (4q..4q+3) of chain (bg*64+i), stream
// ordered (t_local 0..15) x (ch 0..2). Lane-coalesced on both sides.

__global__ __launch_bounds__(256, 2) void fused_kernel(
    const float* __restrict__ x,
    const float* __restrict__ w0f,
    const float* __restrict__ w1f,
    const float* __restrict__ w2f,
    float* __restrict__ u_out,        // [B][K][T] f32
    float* __restrict__ s_out,        // [B][K][T] f32
    float* __restrict__ w32,          // panel
    unsigned* __restrict__ flags)     // [4 bg][128 tt] conv-tile-done flags
{
    // LDS union: conv branch uses sx (41,984 B); scan branch uses
    // lbuf+sstage (49,344 B). Union 49,344 B -> 2 blocks/CU.
    __shared__ union SH {
        struct { float sx[64][164]; } c;
        struct { float4 lbuf[3 * 768]; float4 sstage[12 * 65]; } s;
    } sh;

    const int tid = threadIdx.x;
    const int bid = blockIdx.x;

    if (bid < 512) {
        // ===================================================================
        // CONV tile (R10-exact) + flag publish.
        // ===================================================================
        const int blk = bid;
        const int bgi = blk >> 7;              // 4 b-tiles
        const int t0  = (blk & 127) * CBT;     // 128 t-tiles
        const int b0  = bgi * 64;

        for (int k = tid; k < 64 * 40; k += 256) {
            const int r  = k / 40;
            const int c4 = k - r * 40;
            const int g  = t0 - 32 + 4 * c4;
            float4 v = make_float4(0.f, 0.f, 0.f, 0.f);
            if (g >= 0) v = *(const float4*)(x + (size_t)(b0 + r) * T + g);
            *(float4*)&sh.c.sx[r][4 * c4] = v;
        }
        __syncthreads();

        const int lane    = tid & 63;
        const int w       = tid >> 6;
        const int t_start = t0 + CWT * w;

        double w0d[8], w1d[16], w2d[32];
#pragma unroll
        for (int i = 0; i < 8; ++i)  w0d[i] = (double)w0f[i];
#pragma unroll
        for (int i = 0; i < 16; ++i) w1d[i] = (double)w1f[i];
#pragma unroll
        for (int i = 0; i < 32; ++i) w2d[i] = (double)w2f[i];

        // ring window: win[t & 31] = x[chain][t]
        double win[32];
#pragma unroll
        for (int k = 1; k < 32; ++k) win[k] = (double)sh.c.sx[lane][CWT * w + k];

        const double s8  = 1.0 / sqrt(8.0);
        const double s32 = 1.0 / sqrt(32.0);

        float fr0[16], fr1[16], fr2[16];
        float4 pf;                              // panel float4 batcher
        float* uf = u_out + (size_t)(b0 + lane) * (3 * T);

#define PPUT(v, D) do {                                                       \
    const float _pv = (v);                                                    \
    if (((D) & 3) == 0) pf.x = _pv;                                           \
    else if (((D) & 3) == 1) pf.y = _pv;                                      \
    else if (((D) & 3) == 2) pf.z = _pv;                                      \
    else {                                                                    \
        pf.w = _pv;                                                           \
        *(float4*)(wq + ((D) >> 2) * 256) = pf;                               \
    }                                                                         \
} while (0)

#pragma unroll
        for (int j = 0; j < CWT; ++j) {
            win[j & 31] = (double)sh.c.sx[lane][CWT * w + 32 + j]; // push x[t]
            double a0 = 0.0, a1 = 0.0, a2 = 0.0;
#pragma unroll
            for (int i = 0; i < 8; ++i)  a0 = fma(w0d[i], win[(j + 25 + i) & 31], a0);
#pragma unroll
            for (int i = 0; i < 16; ++i) a1 = fma(w1d[i], win[(j + 17 + i) & 31], a1);
#pragma unroll
            for (int i = 0; i < 32; ++i) a2 = fma(w2d[i], win[(j + 1 + i) & 31], a2);
            a0 *= s8; a1 *= 0.25; a2 *= s32;

            const int t = t_start + j;
            float* wq = w32 + ((size_t)(t >> 4) * 4 + bgi) * 3072 + lane * 4;
            const int D0 = (j & 15) * 3;                        // t&15 == j&15
            PPUT((float)(a0 - 0.05), D0);
            PPUT((float)(a1 - 0.05), D0 + 1);
            PPUT((float)(a2 - 0.05), D0 + 2);

            fr0[j & 15] = (float)a0; fr1[j & 15] = (float)a1; fr2[j & 15] = (float)a2;
            if ((j & 15) == 15) {
                float* d = uf + t_start + (j & ~15);
#pragma unroll
                for (int q = 0; q < 4; ++q) {
                    *(float4*)(d + 4 * q)         = ((float4*)fr0)[q];
                    *(float4*)(d + T + 4 * q)     = ((float4*)fr1)[q];
                    *(float4*)(d + 2 * T + 4 * q) = ((float4*)fr2)[q];
                }
            }
        }
#undef PPUT

        // Publish: all 4 waves' panel stores device-visible, then one
        // agent-scope release store of the tile flag.
        __threadfence();
        __syncthreads();
        if (tid == 0)
            __hip_atomic_store(flags + blk, 1u, __ATOMIC_RELEASE,
                               __HIP_MEMORY_SCOPE_AGENT);
        return;
    }

    // =======================================================================
    // SCAN task (R10-exact), gated on producer flags.
    // =======================================================================
    if (tid >= 64) return;                  // wave 0 only

    const int phys = bid - 512;             // 0..511
    const int xcd  = phys & 7;
    const int slot = phys >> 3;             // 0..63
    const int c    = xcd * 16 + (slot & 15);    // 0..127
    const int bg   = slot >> 4;                 // 0..3
    const int lane = tid;

    const int t_emit = c * CHUNK;
    const int t_w    = (t_emit >= WARM) ? (t_emit - WARM) : 0;
    const int warm_g = (t_emit - t_w) >> 4;     // 0, 8, 16, 24, or 32
    const int n_g    = warm_g + (CHUNK >> 4);   // 8 .. 40
    const int tw16   = t_w >> 4;

    // Wait for the conv tiles covering groups [tw16, tw16+n_g): tiles are
    // 8 groups each and tw16 is a multiple of 8 -> at most 5 tiles.
    // Acquire loads double as the cross-XCD / cross-replay cache acquire.
    {
        const int first_t = tw16 >> 3;
        const int last_t  = (tw16 + n_g - 1) >> 3;
        for (int tt = first_t; tt <= last_t; ++tt) {
            const unsigned* f = flags + bg * 128 + tt;
            while (__hip_atomic_load(f, __ATOMIC_ACQUIRE,
                                     __HIP_MEMORY_SCOPE_AGENT) == 0u)
                __builtin_amdgcn_s_sleep(8);
        }
    }

    float4* lbuf   = sh.s.lbuf;
    float4* sstage = sh.s.sstage;

    double m0 = -1.0, m1 = -1.0, m2 = -1.0;     // v=0 -> m=-1 exactly

#define WAITN(N) do {                                                   \
    asm volatile("s_waitcnt vmcnt(" #N ")" ::: "memory");               \
    __builtin_amdgcn_sched_barrier(0);                                  \
} while (0)

#define LOADDMA(s, gg) do {                                                   \
    const float4* _src = (const float4*)(w32 +                                \
        ((size_t)(tw16 + (gg)) * 4 + bg) * 3072) + lane;                      \
    _Pragma("unroll")                                                         \
    for (int _q = 0; _q < 12; ++_q)                                           \
        __builtin_amdgcn_global_load_lds(                                     \
            (const __attribute__((address_space(1))) void*)(const void*)      \
                (_src + (size_t)_q * 64),                                     \
            (__attribute__((address_space(3))) void*)(void*)                  \
                (&lbuf[(s) * 768 + _q * 64]),                                 \
            16, 0, 0);                                                        \
} while (0)

#define STEP(W0, W1, W2, O0, O1, O2) do {                               \
    const double M0 = fma(0.95, m0, (W0));                              \
    const double M1 = fma(0.95, m1, (W1));                              \
    const double M2 = fma(0.95, m2, (W2));                              \
    const bool c01 = (M0 >= M1);                                        \
    const bool c02 = (M0 >= M2);                                        \
    const bool c12 = (M1 >= M2);                                        \
    const bool f0  = (M0 >= 0.0);                                       \
    const bool f1  = (M1 >= 0.0);                                       \
    const bool f2  = (M2 >= 0.0);                                       \
    const bool s0 = c01 & c02 & f0;          /* first-index argmax */   \
    const bool s1 = (!c01) & c12 & f1;                                  \
    const bool s2 = (!c02) & (!c12) & f2;                               \
    m0 = s0 ? M0 - 1.0 : M0;                                            \
    m1 = s1 ? M1 - 1.0 : M1;                                            \
    m2 = s2 ? M2 - 1.0 : M2;                                            \
    (O0) = s0 ? 1.0f : 0.0f;                                            \
    (O1) = s1 ? 1.0f : 0.0f;                                            \
    (O2) = s2 ? 1.0f : 0.0f;                                            \
} while (0)

#define GETW(d) ( ((d) & 3) == 0 ? _rf[(d) >> 2].x                      \
                : ((d) & 3) == 1 ? _rf[(d) >> 2].y                      \
                : ((d) & 3) == 2 ? _rf[(d) >> 2].z                      \
                :                  _rf[(d) >> 2].w )

// Wait-count table (R15-corrected, proven R9/R10): newer(L(p)) =
// stores(p-3)+L(p+1)+stores(p-2)+L(p+2)+stores(p-1).
#define BODY(s, pp) do {                                                      \
    if ((pp) < n_g) {                                                         \
        if ((pp) == n_g - 1)            WAITN(36);                            \
        else if ((pp) == n_g - 2)       WAITN(48);                            \
        else if ((pp) >= warm_g + 3)    WAITN(60);                            \
        else if ((pp) == warm_g + 2)    WAITN(48);                            \
        else if ((pp) == warm_g + 1)    WAITN(36);                            \
        else                            WAITN(24);                            \
        const float4* _lp = lbuf + (s) * 768 + lane;                          \
        float4 _rf[12];                                                       \
        _Pragma("unroll")                                                     \
        for (int _q = 0; _q < 12; ++_q) _rf[_q] = _lp[(size_t)_q * 64];       \
        float sp0[16], sp1[16], sp2[16];                                      \
        _Pragma("unroll")                                                     \
        for (int _j = 0; _j < 16; ++_j) {                                     \
            const int _d0 = 3 * _j;                                           \
            const double _W0 = (double)GETW(_d0);                             \
            const double _W1 = (double)GETW(_d0 + 1);                         \
            const double _W2 = (double)GETW(_d0 + 2);                         \
            STEP(_W0, _W1, _W2, sp0[_j], sp1[_j], sp2[_j]);                   \
        }                                                                     \
        if ((pp) + 3 < n_g) LOADDMA(s, (pp) + 3);                             \
        if ((pp) >= warm_g) {                                                 \
            _Pragma("unroll")                                                 \
            for (int _q = 0; _q < 4; ++_q) {                                  \
                sstage[(0 * 4 + _q) * 65 + lane] = ((float4*)sp0)[_q];        \
                sstage[(1 * 4 + _q) * 65 + lane] = ((float4*)sp1)[_q];        \
                sstage[(2 * 4 + _q) * 65 + lane] = ((float4*)sp2)[_q];        \
            }                                                                 \
            asm volatile("s_waitcnt lgkmcnt(0)" ::: "memory");                \
            __builtin_amdgcn_sched_barrier(0);                                \
            const int _t = t_w + (pp) * 16;                                   \
            _Pragma("unroll")                                                 \
            for (int _k = 0; _k < 3; ++_k) {                                  \
                _Pragma("unroll")                                             \
                for (int _g = 0; _g < 4; ++_g) {                              \
                    const float4 _v =                                         \
                        sstage[(_k * 4 + (lane & 3)) * 65 + _g * 16 + (lane >> 2)]; \
                    float* _dst = s_out                                       \
                        + (size_t)(bg * 64 + _g * 16 + (lane >> 2)) * (3 * T) \
                        + (size_t)_k * T + _t + (lane & 3) * 4;               \
                    *(float4*)_dst = _v;                                      \
                }                                                             \
            }                                                                 \
        }                                                                     \
    }                                                                         \
} while (0)

    LOADDMA(0, 0);
    LOADDMA(1, 1);
    LOADDMA(2, 2);
    for (int p = 0; p < 48; p += 3) {
        if (p >= n_g) break;
        BODY(0, p);
        BODY(1, p + 1);
        BODY(2, p + 2);
    }

#undef BODY
#undef GETW
#undef STEP
#undef LOADDMA
#undef WAITN
}

// ---------------------------------------------------------------------------
extern "C" void kernel_launch(void* const* d_in, const int* in_sizes, int n_in,
                              void* d_out, int out_size, void* d_ws, size_t ws_size,
                              hipStream_t stream)
{
    const float* x  = (const float*)d_in[0];
    const float* w0 = (const float*)d_in[1];
    const float* w1 = (const float*)d_in[2];
    const float* w2 = (const float*)d_in[3];
    // d_in[4] = y (unused by the reference outputs)

    float* out   = (float*)d_out;
    float* u_out = out;                        // [B][K][T]
    float* s_out = out + (size_t)B * K * T;    // [B][K][T]

    float*    w32   = (float*)d_ws;                          // 50.3 MB panel
    unsigned* flags = (unsigned*)((char*)d_ws + (64u << 20)); // 2 KB flags

    // Reset flags each launch/replay (captured into the graph).
    hipMemsetAsync(flags, 0, 512 * sizeof(unsigned), stream);

    fused_kernel<<<1024, 256, 0, stream>>>(
        x, w0, w1, w2, u_out, s_out, w32, flags);
}

// Round 14
// 195.060 us; speedup vs baseline: 1.7869x; 1.7869x over previous
//
#include <hip/hip_runtime.h>
#include <math.h>

// Problem constants (match reference)
constexpr int B = 256;
constexpr int T = 16384;
constexpr int K = 3;

// R20 = R19 with the u-staging layout fix. R19's u pass staged _rf (STREAM
// order: float4 q = stream floats 4q..4q+3, D = 3t+ch interleaved) directly
// into sstage, but TSTORE expects CHANNEL-major slabs (slab k*4+tq = channel
// k, times 4tq..4tq+3) -> u scrambled, absmax 3.08. Fix: rebuild channel-
// major fu_k[j] = W_k(j) + 0.05f (48 adds) and stage exactly like the
// (R10-proven) s pass. fl(fl(a-0.05)+0.05) vs fl(a) <= ~2ulp ~ 3e-7.
//
// R19 rationale (base = R10/208us): conv is write-throughput-bound (146 MB
// stores for ~6us f64 math); u and panel are redundant encodings
// (u = W + 0.05) and the scan's emit windows tile all groups exactly once
// -> conv writes ONLY the 50 MB panel, scan emits BOTH s and u.
constexpr int CHUNK = 128;
constexpr int WARM  = 512;

// Conv tiling: 64 chains x 128 timesteps per block, 4 waves x 32 t each.
constexpr int CBT = 128;
constexpr int CWT = 32;

// w32 panel layout [T/16][4 bg][12 q][64 lane] x 16B (float4):
// float4 q of lane i = stream floats (4q..4q+3) of chain (bg*64+i), stream
// ordered (t_local 0..15) x (ch 0..2). Lane-coalesced on both sides.

// ---------------------------------------------------------------------------
// Conv: causal k=8/16/32 in f64 (same tap order / fma / scale as R2-R10).
// PANEL ONLY (u emitted by the scan). PPUT register-batched float4 stores,
// 1 KB contiguous per instruction.
// ---------------------------------------------------------------------------
__global__ __launch_bounds__(256, 2) void conv_kernel(
    const float* __restrict__ x,
    const float* __restrict__ w0f,
    const float* __restrict__ w1f,
    const float* __restrict__ w2f,
    float*  __restrict__ w32)     // panel layout above
{
    const int blk = blockIdx.x;            // 512 blocks
    const int bgi = blk >> 7;              // 4 b-tiles
    const int t0  = (blk & 127) * CBT;     // 128 t-tiles
    const int b0  = bgi * 64;
    const int tid = threadIdx.x;

    __shared__ float sx[64][164];          // cols t0-32 .. t0+127, +4 pad
    for (int k = tid; k < 64 * 40; k += 256) {
        const int r  = k / 40;
        const int c4 = k - r * 40;
        const int g  = t0 - 32 + 4 * c4;
        float4 v = make_float4(0.f, 0.f, 0.f, 0.f);
        if (g >= 0) v = *(const float4*)(x + (size_t)(b0 + r) * T + g);
        *(float4*)&sx[r][4 * c4] = v;
    }
    __syncthreads();

    const int lane    = tid & 63;
    const int w       = tid >> 6;
    const int t_start = t0 + CWT * w;

    double w0d[8], w1d[16], w2d[32];
#pragma unroll
    for (int i = 0; i < 8; ++i)  w0d[i] = (double)w0f[i];
#pragma unroll
    for (int i = 0; i < 16; ++i) w1d[i] = (double)w1f[i];
#pragma unroll
    for (int i = 0; i < 32; ++i) w2d[i] = (double)w2f[i];

    // ring window: win[t & 31] = x[chain][t]
    double win[32];
#pragma unroll
    for (int k = 1; k < 32; ++k) win[k] = (double)sx[lane][CWT * w + k];

    const double s8  = 1.0 / sqrt(8.0);
    const double s32 = 1.0 / sqrt(32.0);

    float4 pf;                              // panel float4 batcher

// Put stream value v at slot D; flush the float4 when last component lands.
#define PPUT(v, D) do {                                                       \
    const float _pv = (v);                                                    \
    if (((D) & 3) == 0) pf.x = _pv;                                           \
    else if (((D) & 3) == 1) pf.y = _pv;                                      \
    else if (((D) & 3) == 2) pf.z = _pv;                                      \
    else {                                                                    \
        pf.w = _pv;                                                           \
        *(float4*)(wq + ((D) >> 2) * 256) = pf;                               \
    }                                                                         \
} while (0)

#pragma unroll
    for (int j = 0; j < CWT; ++j) {
        win[j & 31] = (double)sx[lane][CWT * w + 32 + j];   // push x[t]
        double a0 = 0.0, a1 = 0.0, a2 = 0.0;
#pragma unroll
        for (int i = 0; i < 8; ++i)  a0 = fma(w0d[i], win[(j + 25 + i) & 31], a0);
#pragma unroll
        for (int i = 0; i < 16; ++i) a1 = fma(w1d[i], win[(j + 17 + i) & 31], a1);
#pragma unroll
        for (int i = 0; i < 32; ++i) a2 = fma(w2d[i], win[(j + 1 + i) & 31], a2);
        a0 *= s8; a1 *= 0.25; a2 *= s32;

        const int t = t_start + j;
        float* wq = w32 + ((size_t)(t >> 4) * 4 + bgi) * 3072 + lane * 4;
        const int D0 = (j & 15) * 3;                        // t&15 == j&15
        PPUT((float)(a0 - 0.05), D0);
        PPUT((float)(a1 - 0.05), D0 + 1);
        PPUT((float)(a2 - 0.05), D0 + 2);
    }
#undef PPUT
}

// ---------------------------------------------------------------------------
// Scan: speculative chunked LIF-WTA, one (chain, chunk) per lane, CHUNK=128
// -> 512 independent 1-wave blocks (2 blocks/CU). f64 state, f32 W.
// LDS-DMA triple buffer + counted vmcnt. Emit phases write BOTH s and
// u (= W + 0.05, channel-major rebuild) via the sstage transpose.
// ---------------------------------------------------------------------------
__global__ __launch_bounds__(64, 1) void scan_kernel(
    const float* __restrict__ w32,
    float* __restrict__ u_out,        // [B][K][T] f32
    float* __restrict__ s_out)        // [B][K][T] f32
{
    // XCD remap: 512 blocks = 8 XCD x 64 slots; XCD k gets c in [16k,16k+16)
    // for each bg (adjacent chunks share 32/40 groups in the XCD L2).
    const int phys = blockIdx.x;
    const int xcd  = phys & 7;
    const int slot = phys >> 3;             // 0..63
    const int c    = xcd * 16 + (slot & 15);    // 0..127
    const int bg   = slot >> 4;                 // 0..3
    const int lane = threadIdx.x;

    const int t_emit = c * CHUNK;
    const int t_w    = (t_emit >= WARM) ? (t_emit - WARM) : 0;
    const int warm_g = (t_emit - t_w) >> 4;     // 0, 8, 16, 24, or 32
    const int n_g    = warm_g + (CHUNK >> 4);   // 8 .. 40
    const int tw16   = t_w >> 4;

    // 3 slabs x 12 KB (one 16-step group each) = 36 KB LDS ring.
    __shared__ float4 lbuf[3 * 768];
    // store-transpose stage: 12 slabs (k*4+q) x 64 chains, +1 float4 pad.
    __shared__ float4 sstage[12 * 65];

    double m0 = -1.0, m1 = -1.0, m2 = -1.0;     // v=0 -> m=-1 exactly

// Counted-vmcnt wait. N <= true count of vmem ops issued after the awaited
// group's last DMA load (lower bound => safe; 63 is the encodable max).
#define WAITN(N) do {                                                   \
    asm volatile("s_waitcnt vmcnt(" #N ")" ::: "memory");               \
    __builtin_amdgcn_sched_barrier(0);                                  \
} while (0)

// DMA one 12 KB group into slab s: 12 instrs, each 64 lanes x 16 B,
// contiguous 1 KB per instruction (panel layout).
#define LOADDMA(s, gg) do {                                                   \
    const float4* _src = (const float4*)(w32 +                                \
        ((size_t)(tw16 + (gg)) * 4 + bg) * 3072) + lane;                      \
    _Pragma("unroll")                                                         \
    for (int _q = 0; _q < 12; ++_q)                                           \
        __builtin_amdgcn_global_load_lds(                                     \
            (const __attribute__((address_space(1))) void*)(const void*)      \
                (_src + (size_t)_q * 64),                                     \
            (__attribute__((address_space(3))) void*)(void*)                  \
                (&lbuf[(s) * 768 + _q * 64]),                                 \
            16, 0, 0);                                                        \
} while (0)

#define STEP(W0, W1, W2, O0, O1, O2) do {                               \
    const double M0 = fma(0.95, m0, (W0));                              \
    const double M1 = fma(0.95, m1, (W1));                              \
    const double M2 = fma(0.95, m2, (W2));                              \
    const bool c01 = (M0 >= M1);                                        \
    const bool c02 = (M0 >= M2);                                        \
    const bool c12 = (M1 >= M2);                                        \
    const bool f0  = (M0 >= 0.0);                                       \
    const bool f1  = (M1 >= 0.0);                                       \
    const bool f2  = (M2 >= 0.0);                                       \
    const bool s0 = c01 & c02 & f0;          /* first-index argmax */   \
    const bool s1 = (!c01) & c12 & f1;                                  \
    const bool s2 = (!c02) & (!c12) & f2;                               \
    m0 = s0 ? M0 - 1.0 : M0;                                            \
    m1 = s1 ? M1 - 1.0 : M1;                                            \
    m2 = s2 ? M2 - 1.0 : M2;                                            \
    (O0) = s0 ? 1.0f : 0.0f;                                            \
    (O1) = s1 ? 1.0f : 0.0f;                                            \
    (O2) = s2 ? 1.0f : 0.0f;                                            \
} while (0)

// Compile-time component select keeps _rf in registers after full unroll.
#define GETW(d) ( ((d) & 3) == 0 ? _rf[(d) >> 2].x                      \
                : ((d) & 3) == 1 ? _rf[(d) >> 2].y                      \
                : ((d) & 3) == 2 ? _rf[(d) >> 2].z                      \
                :                  _rf[(d) >> 2].w )

// Transposed full-line store of the 12 sstage slabs to dst (u or s view).
#define TSTORE(dstbase, tt) do {                                              \
    _Pragma("unroll")                                                         \
    for (int _k = 0; _k < 3; ++_k) {                                          \
        _Pragma("unroll")                                                     \
        for (int _g = 0; _g < 4; ++_g) {                                      \
            const float4 _v =                                                 \
                sstage[(_k * 4 + (lane & 3)) * 65 + _g * 16 + (lane >> 2)];   \
            float* _dst = (dstbase)                                           \
                + (size_t)(bg * 64 + _g * 16 + (lane >> 2)) * (3 * T)         \
                + (size_t)_k * T + (tt) + (lane & 3) * 4;                     \
            *(float4*)_dst = _v;                                              \
        }                                                                     \
    }                                                                         \
} while (0)

#define LGKM0 do {                                                      \
    asm volatile("s_waitcnt lgkmcnt(0)" ::: "memory");                  \
    __builtin_amdgcn_sched_barrier(0);                                  \
} while (0)

// Wait-count table for 24-store emit phases (s + u). Issue order per phase
// p: WAIT -> ds_read -> compute -> LOADDMA(p+3) -> stores(p)=24.
// newer(L(p)) = st(p-3)+L(p+1)+st(p-2)+L(p+2)+st(p-1):
//   warm steady:      24
//   p == warm_g+1:    12+12+24            = 48
//   p >= warm_g+2:    72..96          -> 63 (clamp; still a lower bound)
#define BODY(s, pp) do {                                                      \
    if ((pp) < n_g) {                                                         \
        if ((pp) >= warm_g + 2)         WAITN(63);                            \
        else if ((pp) == warm_g + 1)    WAITN(48);                            \
        else                            WAITN(24);                            \
        const float4* _lp = lbuf + (s) * 768 + lane;                          \
        float4 _rf[12];                                                       \
        _Pragma("unroll")                                                     \
        for (int _q = 0; _q < 12; ++_q) _rf[_q] = _lp[(size_t)_q * 64];       \
        float sp0[16], sp1[16], sp2[16];                                      \
        _Pragma("unroll")                                                     \
        for (int _j = 0; _j < 16; ++_j) {                                     \
            const int _d0 = 3 * _j;                                           \
            const double _W0 = (double)GETW(_d0);                             \
            const double _W1 = (double)GETW(_d0 + 1);                         \
            const double _W2 = (double)GETW(_d0 + 2);                         \
            STEP(_W0, _W1, _W2, sp0[_j], sp1[_j], sp2[_j]);                   \
        }                                                                     \
        if ((pp) + 3 < n_g) LOADDMA(s, (pp) + 3);                             \
        if ((pp) >= warm_g) {                                                 \
            const int _t = t_w + (pp) * 16;                                   \
            /* s pass through sstage (channel-major, R10-proven) */           \
            _Pragma("unroll")                                                 \
            for (int _q = 0; _q < 4; ++_q) {                                  \
                sstage[(0 * 4 + _q) * 65 + lane] = ((float4*)sp0)[_q];        \
                sstage[(1 * 4 + _q) * 65 + lane] = ((float4*)sp1)[_q];        \
                sstage[(2 * 4 + _q) * 65 + lane] = ((float4*)sp2)[_q];        \
            }                                                                 \
            LGKM0;                                                            \
            TSTORE(s_out, _t);                                                \
            LGKM0;  /* sstage reads done before u pass overwrites */          \
            /* u pass: CHANNEL-MAJOR rebuild fu_k[j] = W_k(j) + 0.05f   */    \
            /* (R19 bug: _rf is stream-order, NOT TSTORE's layout)      */    \
            float fu0[16], fu1[16], fu2[16];                                  \
            _Pragma("unroll")                                                 \
            for (int _j = 0; _j < 16; ++_j) {                                 \
                const int _d0 = 3 * _j;                                       \
                fu0[_j] = GETW(_d0)     + 0.05f;                              \
                fu1[_j] = GETW(_d0 + 1) + 0.05f;                              \
                fu2[_j] = GETW(_d0 + 2) + 0.05f;                              \
            }                                                                 \
            _Pragma("unroll")                                                 \
            for (int _q = 0; _q < 4; ++_q) {                                  \
                sstage[(0 * 4 + _q) * 65 + lane] = ((float4*)fu0)[_q];        \
                sstage[(1 * 4 + _q) * 65 + lane] = ((float4*)fu1)[_q];        \
                sstage[(2 * 4 + _q) * 65 + lane] = ((float4*)fu2)[_q];        \
            }                                                                 \
            LGKM0;                                                            \
            TSTORE(u_out, _t);                                                \
            LGKM0;  /* u reads done before next phase's s pass */             \
        }                                                                     \
    }                                                                         \
} while (0)

    LOADDMA(0, 0);
    LOADDMA(1, 1);
    LOADDMA(2, 2);
    for (int p = 0; p < 48; p += 3) {
        if (p >= n_g) break;
        BODY(0, p);
        BODY(1, p + 1);
        BODY(2, p + 2);
    }

#undef BODY
#undef LGKM0
#undef TSTORE
#undef GETW
#undef STEP
#undef LOADDMA
#undef WAITN
}

// ---------------------------------------------------------------------------
extern "C" void kernel_launch(void* const* d_in, const int* in_sizes, int n_in,
                              void* d_out, int out_size, void* d_ws, size_t ws_size,
                              hipStream_t stream)
{
    const float* x  = (const float*)d_in[0];
    const float* w0 = (const float*)d_in[1];
    const float* w1 = (const float*)d_in[2];
    const float* w2 = (const float*)d_in[3];
    // d_in[4] = y (unused by the reference outputs)

    float* out   = (float*)d_out;
    float* u_out = out;                        // [B][K][T]
    float* s_out = out + (size_t)B * K * T;    // [B][K][T]

    float* w32 = (float*)d_ws;                 // 50.3 MB f32 panel

    conv_kernel<<<(B / 64) * (T / CBT), 256, 0, stream>>>(x, w0, w1, w2, w32);
    scan_kernel<<<(B / 64) * (T / CHUNK), 64, 0, stream>>>(w32, u_out, s_out);
}